// Round 1
// baseline (1577.399 us; speedup 1.0000x reference)
//
#include <hip/hip_runtime.h>
#include <hip/hip_bf16.h>
#include <cstdint>
#include <cstddef>

// MultiGateMixExperts: 3 batched fp16-MFMA GEMM stages + tiny epilogue kernels.
// Sizes: B=8192, D=H=1024, E=16, L=2.
// h1 = sigmoid(x@W1[e]+b1)            (sigmoid>0 => relu(h1)==h1)
// h2 = relu(h1@W2[e]+b2)  (store relu'd; h2 raw never needed downstream)
// h3 = h2@W2[e]+b2
// f  = h3.Wo[e]+bo ; out_i = softmax(x@Wg_i+bg_i) . f

using half8  = __attribute__((ext_vector_type(8))) _Float16;
using floatx4 = __attribute__((ext_vector_type(4))) float;

typedef const __attribute__((address_space(1))) uint32_t* gas1_t;
typedef __attribute__((address_space(3))) uint32_t* las3_t;

__device__ __forceinline__ void gld_lds16(const void* g, void* l) {
    // lane i writes LDS at (uniform base) + i*16; 16B per lane.
    __builtin_amdgcn_global_load_lds((gas1_t)g, (las3_t)l, 16, 0, 0);
}

// ---------------------------------------------------------------- GEMM ------
// C[m,n] = act( sum_k A[m,k]*Bt[n,k] + bias[n] ), M=8192, N=K=1024.
// ACT: 0=sigmoid, 1=relu, 2=none. blockIdx.z = local expert.
// LDS tiles 128x64 fp16, 16B chunks XOR-swizzled: chunk(row, pcol) holds
// logical k-chunk (pcol ^ (row&7)) -> ds_read_b128 frag loads are bank-balanced.
template<int ACT>
__global__ __launch_bounds__(256)
void gemm_kernel(const _Float16* __restrict__ A, const _Float16* __restrict__ Bt,
                 const float* __restrict__ bias, _Float16* __restrict__ C,
                 size_t a_estride)
{
    __shared__ _Float16 As[128 * 64];
    __shared__ _Float16 Bs[128 * 64];

    const int tid  = threadIdx.x;
    const int lane = tid & 63;
    const int w    = tid >> 6;      // wave 0..3
    const int wm   = w & 1;         // 2x2 wave grid over 128x128
    const int wn   = w >> 1;
    const int le   = blockIdx.z;
    const int m0   = blockIdx.y * 128;
    const int n0   = blockIdx.x * 128;

    const _Float16* Ae = A   + (size_t)le * a_estride;
    const _Float16* Be = Bt  + (size_t)le * (1024ull * 1024ull);
    const float*    be = bias + (size_t)le * 1024ull;
    _Float16*       Ce = C   + (size_t)le * (8192ull * 1024ull);

    // --- staging addresses (global side carries the XOR swizzle) ---
    const int pcol = lane & 7;        // physical 16B chunk within row
    const int rlo  = lane >> 3;       // row low bits 0..7
    const int k8s  = pcol ^ rlo;      // logical k-chunk stored at this slot
    const _Float16* gA[4]; const _Float16* gB[4];
    _Float16* lA[4]; _Float16* lB[4];
#pragma unroll
    for (int c = 0; c < 4; ++c) {
        const int row = w * 32 + c * 8 + rlo;               // 0..127
        gA[c] = Ae + (size_t)(m0 + row) * 1024 + k8s * 8;
        gB[c] = Be + (size_t)(n0 + row) * 1024 + k8s * 8;
        lA[c] = As + (w * 256 + c * 64) * 8;                // wave-uniform base
        lB[c] = Bs + (w * 256 + c * 64) * 8;
    }

    floatx4 acc[4][4];
#pragma unroll
    for (int i = 0; i < 4; ++i)
#pragma unroll
        for (int j = 0; j < 4; ++j) { floatx4 z = {0.f, 0.f, 0.f, 0.f}; acc[i][j] = z; }

    const int q   = lane >> 4;   // quad 0..3
    const int l7  = lane & 7;
    const int l15 = lane & 15;
    int aoff[4], boff[4];
#pragma unroll
    for (int i = 0; i < 4; ++i) {
        aoff[i] = (wm * 64 + i * 16 + l15) * 64;   // row base in halves
        boff[i] = (wn * 64 + i * 16 + l15) * 64;
    }

    for (int kt = 0; kt < 16; ++kt) {
        __syncthreads();                       // protect LDS from overwrite
        const int kg = kt * 64;
#pragma unroll
        for (int c = 0; c < 4; ++c) {
            gld_lds16(gA[c] + kg, lA[c]);
            gld_lds16(gB[c] + kg, lB[c]);
        }
        __syncthreads();                       // drains vmcnt(0)
#pragma unroll
        for (int kk = 0; kk < 2; ++kk) {
            const int kidx = ((kk * 4 + q) ^ l7) * 8;  // swizzled chunk -> halves
            half8 af[4], bf[4];
#pragma unroll
            for (int i = 0; i < 4; ++i) af[i] = *(const half8*)(As + aoff[i] + kidx);
#pragma unroll
            for (int j = 0; j < 4; ++j) bf[j] = *(const half8*)(Bs + boff[j] + kidx);
#pragma unroll
            for (int i = 0; i < 4; ++i)
#pragma unroll
                for (int j = 0; j < 4; ++j)
                    acc[i][j] = __builtin_amdgcn_mfma_f32_16x16x32_f16(af[i], bf[j], acc[i][j], 0, 0, 0);
        }
    }

    // epilogue: C/D layout col=lane&15, row=q*4+r (dtype-independent, m89/m121)
    float bj[4];
#pragma unroll
    for (int j = 0; j < 4; ++j) bj[j] = be[n0 + wn * 64 + j * 16 + l15];
#pragma unroll
    for (int i = 0; i < 4; ++i) {
        const int mbase = m0 + wm * 64 + i * 16 + q * 4;
#pragma unroll
        for (int r = 0; r < 4; ++r) {
            const size_t rowoff = (size_t)(mbase + r) * 1024;
#pragma unroll
            for (int j = 0; j < 4; ++j) {
                float v = acc[i][j][r] + bj[j];
                if (ACT == 0)      v = 1.0f / (1.0f + __expf(-v));
                else if (ACT == 1) v = fmaxf(v, 0.0f);
                Ce[rowoff + n0 + wn * 64 + j * 16 + l15] = (_Float16)v;
            }
        }
    }
}

// ---------------------------------------------------- cast x to fp16 --------
__global__ __launch_bounds__(256)
void castx_kernel(const float* __restrict__ x, _Float16* __restrict__ xb)
{
    const size_t i = ((size_t)blockIdx.x * 256 + threadIdx.x) * 8;
    float4 a = *(const float4*)(x + i);
    float4 b = *(const float4*)(x + i + 4);
    half8 h;
    h[0] = (_Float16)a.x; h[1] = (_Float16)a.y; h[2] = (_Float16)a.z; h[3] = (_Float16)a.w;
    h[4] = (_Float16)b.x; h[5] = (_Float16)b.y; h[6] = (_Float16)b.z; h[7] = (_Float16)b.w;
    *(half8*)(xb + i) = h;
}

// --------------------------- transpose+cast W1/W2 -> [E][N][K] fp16 ---------
__global__ __launch_bounds__(256)
void transpose_kernel(const float* __restrict__ W1, const float* __restrict__ W2,
                      _Float16* __restrict__ W1T, _Float16* __restrict__ W2T)
{
    __shared__ _Float16 tile[64][65];
    const int z = blockIdx.z;
    const float* src = (z < 16) ? (W1 + (size_t)z * 1048576ull) : (W2 + (size_t)(z - 16) * 1048576ull);
    _Float16*    dst = (z < 16) ? (W1T + (size_t)z * 1048576ull) : (W2T + (size_t)(z - 16) * 1048576ull);
    const int d0 = blockIdx.y * 64, h0 = blockIdx.x * 64;
    const int tx = threadIdx.x & 63, ty = threadIdx.x >> 6;
#pragma unroll
    for (int r = 0; r < 16; ++r) {
        const int row = r * 4 + ty;
        tile[row][tx] = (_Float16)src[(size_t)(d0 + row) * 1024 + h0 + tx];
    }
    __syncthreads();
#pragma unroll
    for (int r = 0; r < 16; ++r) {
        const int hrow = r * 4 + ty;
        dst[(size_t)(h0 + hrow) * 1024 + d0 + tx] = tile[tx][hrow];
    }
}

// ------------------------------------- f[b,e] = h3[e,b,:].Wo[e] + bo[e] -----
__global__ __launch_bounds__(256)
void fpart_kernel(const _Float16* __restrict__ h3, const float* __restrict__ Wo,
                  const float* __restrict__ bo, float* __restrict__ f,
                  int e0, int g)
{
    const int lane = threadIdx.x & 63;
    const int w    = threadIdx.x >> 6;
    const int b    = blockIdx.x * 4 + w;
    for (int le = 0; le < g; ++le) {
        const _Float16* hp = h3 + ((size_t)le * 8192 + b) * 1024;
        const float*    wp = Wo + (size_t)(e0 + le) * 1024;
        float acc = 0.f;
#pragma unroll
        for (int it = 0; it < 2; ++it) {
            const int off = it * 512 + lane * 8;
            half8 hv = *(const half8*)(hp + off);
            float4 w0 = *(const float4*)(wp + off);
            float4 w1 = *(const float4*)(wp + off + 4);
            acc += (float)hv[0] * w0.x + (float)hv[1] * w0.y + (float)hv[2] * w0.z + (float)hv[3] * w0.w
                 + (float)hv[4] * w1.x + (float)hv[5] * w1.y + (float)hv[6] * w1.z + (float)hv[7] * w1.w;
        }
#pragma unroll
        for (int m = 1; m < 64; m <<= 1) acc += __shfl_xor(acc, m, 64);
        if (lane == 0) f[(size_t)b * 16 + e0 + le] = acc + bo[e0 + le];
    }
}

// ------------------ gates (fp32, full precision) + softmax + combine --------
__global__ __launch_bounds__(256)
void final_kernel(const float* __restrict__ x,
                  const float* __restrict__ Wg1, const float* __restrict__ bg1,
                  const float* __restrict__ Wg2, const float* __restrict__ bg2,
                  const float* __restrict__ f, float* __restrict__ out)
{
    const int lane = threadIdx.x & 63;
    const int w    = threadIdx.x >> 6;
    const int b    = blockIdx.x * 4 + w;
    const float* xr = x + (size_t)b * 1024;
    float gp1[16], gp2[16];
#pragma unroll
    for (int e = 0; e < 16; ++e) { gp1[e] = 0.f; gp2[e] = 0.f; }
    for (int t = 0; t < 16; ++t) {
        const int d = t * 64 + lane;                 // coalesced x reads
        const float xv = xr[d];
        const float* w1r = Wg1 + (size_t)d * 16;
        const float* w2r = Wg2 + (size_t)d * 16;
#pragma unroll
        for (int e = 0; e < 16; ++e) { gp1[e] += xv * w1r[e]; gp2[e] += xv * w2r[e]; }
    }
#pragma unroll
    for (int e = 0; e < 16; ++e) {
#pragma unroll
        for (int m = 1; m < 64; m <<= 1) {
            gp1[e] += __shfl_xor(gp1[e], m, 64);
            gp2[e] += __shfl_xor(gp2[e], m, 64);
        }
    }
    float a1[16], a2[16], m1 = -1e30f, m2 = -1e30f;
#pragma unroll
    for (int e = 0; e < 16; ++e) {
        a1[e] = gp1[e] + bg1[e]; m1 = fmaxf(m1, a1[e]);
        a2[e] = gp2[e] + bg2[e]; m2 = fmaxf(m2, a2[e]);
    }
    float s1 = 0.f, s2 = 0.f;
#pragma unroll
    for (int e = 0; e < 16; ++e) {
        a1[e] = __expf(a1[e] - m1); s1 += a1[e];
        a2[e] = __expf(a2[e] - m2); s2 += a2[e];
    }
    float o1 = 0.f, o2 = 0.f;
    const float* fb = f + (size_t)b * 16;
#pragma unroll
    for (int e = 0; e < 16; ++e) { const float fe = fb[e]; o1 += a1[e] * fe; o2 += a2[e] * fe; }
    if (lane == 0) { out[b] = o1 / s1; out[8192 + b] = o2 / s2; }
}

// ----------------------------------------------------------------------------
extern "C" void kernel_launch(void* const* d_in, const int* in_sizes, int n_in,
                              void* d_out, int out_size, void* d_ws, size_t ws_size,
                              hipStream_t stream)
{
    const float* x   = (const float*)d_in[0];
    const float* W1  = (const float*)d_in[1];
    const float* b1  = (const float*)d_in[2];
    const float* W2  = (const float*)d_in[3];
    const float* b2  = (const float*)d_in[4];
    const float* Wo  = (const float*)d_in[5];
    const float* bo  = (const float*)d_in[6];
    const float* Wg1 = (const float*)d_in[7];
    const float* bg1 = (const float*)d_in[8];
    const float* Wg2 = (const float*)d_in[9];
    const float* bg2 = (const float*)d_in[10];
    float* out = (float*)d_out;

    char* ws = (char*)d_ws;
    _Float16* xb  = (_Float16*)(ws);                         // 16 MB
    _Float16* W1T = (_Float16*)(ws + 16777216ull);           // 32 MB
    _Float16* W2T = (_Float16*)(ws + 50331648ull);           // 32 MB
    float*    f   = (float*)   (ws + 83886080ull);           // 0.5 MB
    char* hbase = ws + 84410368ull;

    // expert-group size: largest that fits ws (deterministic per ws_size)
    int g = 1;
    const int cands[4] = {16, 8, 4, 2};
    for (int ci = 0; ci < 4; ++ci) {
        const size_t need = 84410368ull + 2ull * cands[ci] * 16777216ull;
        if (need <= ws_size) { g = cands[ci]; break; }
    }
    _Float16* h0 = (_Float16*)hbase;
    _Float16* h1 = (_Float16*)(hbase + (size_t)g * 16777216ull);

    castx_kernel<<<4096, 256, 0, stream>>>(x, xb);
    transpose_kernel<<<dim3(16, 16, 32), 256, 0, stream>>>(W1, W2, W1T, W2T);

    for (int e0 = 0; e0 < 16; e0 += g) {
        gemm_kernel<0><<<dim3(8, 64, g), 256, 0, stream>>>(
            xb, W1T + (size_t)e0 * 1048576ull, b1 + (size_t)e0 * 1024, h0, 0);
        gemm_kernel<1><<<dim3(8, 64, g), 256, 0, stream>>>(
            h0, W2T + (size_t)e0 * 1048576ull, b2 + (size_t)e0 * 1024, h1, 8192ull * 1024ull);
        gemm_kernel<2><<<dim3(8, 64, g), 256, 0, stream>>>(
            h1, W2T + (size_t)e0 * 1048576ull, b2 + (size_t)e0 * 1024, h0, 8192ull * 1024ull);
        fpart_kernel<<<2048, 256, 0, stream>>>(h0, Wo, bo, f, e0, g);
    }
    final_kernel<<<2048, 256, 0, stream>>>(x, Wg1, bg1, Wg2, bg2, f, out);
}

// Round 2
// 1382.106 us; speedup vs baseline: 1.1413x; 1.1413x over previous
//
#include <hip/hip_runtime.h>
#include <hip/hip_bf16.h>
#include <cstdint>
#include <cstddef>

// MultiGateMixExperts: 3 batched fp16-MFMA GEMM stages + tiny epilogue kernels.
// Sizes: B=8192, D=H=1024, E=16, L=2.
// h1 = sigmoid(x@W1[e]+b1)
// h2 = relu(h1@W2[e]+b2)
// f  = (h2@W2[e]+b2).Wo[e]  (fused into stage-3 epilogue, atomicAdd over n-blocks)
// out_i = softmax(x@Wg_i+bg_i) . (f+bo)

using half8  = __attribute__((ext_vector_type(8))) _Float16;
using floatx4 = __attribute__((ext_vector_type(4))) float;

typedef const __attribute__((address_space(1))) uint32_t* gas1_t;
typedef __attribute__((address_space(3))) uint32_t* las3_t;

__device__ __forceinline__ void gld_lds16(const void* g, void* l) {
    // lane i writes LDS at (uniform base) + i*16; 16B per lane.
    __builtin_amdgcn_global_load_lds((gas1_t)g, (las3_t)l, 16, 0, 0);
}

// ---------------------------------------------------------------- GEMM ------
// C[m,n] = act( sum_k A[m,k]*Bt[n,k] + bias[n] ), M=8192, N=K=1024.
// ACT: 0=sigmoid, 1=relu, 2=f-fused (no C store; f[m,e] += (C+b2).Wo).
// blockIdx decoded via XCD-aware remap: flat%8 = XCD; each XCD gets one
// expert x contiguous M-stripe x all N  -> per-XCD L2 working set ~6MB.
// LDS tiles 128x64 fp16, 16B chunks XOR-swizzled (global side carries swizzle).
template<int ACT>
__global__ __launch_bounds__(256)
void gemm_kernel(const _Float16* __restrict__ A, const _Float16* __restrict__ Bt,
                 const float* __restrict__ bias, _Float16* __restrict__ C,
                 size_t a_estride,
                 const float* __restrict__ Wo, float* __restrict__ f, int e0)
{
    __shared__ _Float16 As[128 * 64];
    __shared__ _Float16 Bs[128 * 64];

    const int tid  = threadIdx.x;
    const int lane = tid & 63;
    const int w    = tid >> 6;      // wave 0..3
    const int wm   = w & 1;         // 2x2 wave grid over 128x128
    const int wn   = w >> 1;

    // --- XCD-aware remap (gridDim = {8, 64, g}) ---
    const int g    = gridDim.z;
    const int flat = blockIdx.x + (blockIdx.y << 3) + (blockIdx.z << 9);
    const int xcd  = flat & 7;
    int s = flat >> 3;
    int le, mb, nb;
    if (g <= 8) {
        const int p = 8 / g;            // XCDs per expert
        le = xcd / p;
        const int stripe = xcd % p;
        nb = s & 7;
        mb = stripe * (64 / p) + (s >> 3);
    } else {                            // g == 16
        le = (xcd << 1) | (s >> 9);
        s &= 511;
        nb = s & 7;
        mb = s >> 3;
    }
    const int m0 = mb * 128;
    const int n0 = nb * 128;

    const _Float16* Ae = A   + (size_t)le * a_estride;
    const _Float16* Be = Bt  + (size_t)le * (1024ull * 1024ull);
    const float*    be = bias + (size_t)le * 1024ull;
    _Float16*       Ce = C   + (size_t)le * (8192ull * 1024ull);

    // --- staging addresses (global side carries the XOR swizzle) ---
    const int pcol = lane & 7;        // physical 16B chunk within row
    const int rlo  = lane >> 3;       // row low bits 0..7
    const int k8s  = pcol ^ rlo;      // logical k-chunk stored at this slot
    const _Float16* gA[4]; const _Float16* gB[4];
    _Float16* lA[4]; _Float16* lB[4];
#pragma unroll
    for (int c = 0; c < 4; ++c) {
        const int row = w * 32 + c * 8 + rlo;               // 0..127
        gA[c] = Ae + (size_t)(m0 + row) * 1024 + k8s * 8;
        gB[c] = Be + (size_t)(n0 + row) * 1024 + k8s * 8;
        lA[c] = As + (w * 256 + c * 64) * 8;                // wave-uniform base
        lB[c] = Bs + (w * 256 + c * 64) * 8;
    }

    floatx4 acc[4][4];
#pragma unroll
    for (int i = 0; i < 4; ++i)
#pragma unroll
        for (int j = 0; j < 4; ++j) { floatx4 z = {0.f, 0.f, 0.f, 0.f}; acc[i][j] = z; }

    const int q   = lane >> 4;   // quad 0..3
    const int l7  = lane & 7;
    const int l15 = lane & 15;
    int aoff[4], boff[4];
#pragma unroll
    for (int i = 0; i < 4; ++i) {
        aoff[i] = (wm * 64 + i * 16 + l15) * 64;   // row base in halves
        boff[i] = (wn * 64 + i * 16 + l15) * 64;
    }

    for (int kt = 0; kt < 16; ++kt) {
        __syncthreads();                       // protect LDS from overwrite
        const int kg = kt * 64;
#pragma unroll
        for (int c = 0; c < 4; ++c) {
            gld_lds16(gA[c] + kg, lA[c]);
            gld_lds16(gB[c] + kg, lB[c]);
        }
        __syncthreads();                       // drains vmcnt(0)
#pragma unroll
        for (int kk = 0; kk < 2; ++kk) {
            const int kidx = ((kk * 4 + q) ^ l7) * 8;  // swizzled chunk -> halves
            half8 af[4], bf[4];
#pragma unroll
            for (int i = 0; i < 4; ++i) af[i] = *(const half8*)(As + aoff[i] + kidx);
#pragma unroll
            for (int j = 0; j < 4; ++j) bf[j] = *(const half8*)(Bs + boff[j] + kidx);
#pragma unroll
            for (int i = 0; i < 4; ++i)
#pragma unroll
                for (int j = 0; j < 4; ++j)
                    acc[i][j] = __builtin_amdgcn_mfma_f32_16x16x32_f16(af[i], bf[j], acc[i][j], 0, 0, 0);
        }
    }

    // epilogue: C/D layout col=lane&15, row=q*4+r (dtype-independent, m89/m121)
    float bj[4];
#pragma unroll
    for (int j = 0; j < 4; ++j) bj[j] = be[n0 + wn * 64 + j * 16 + l15];

    if (ACT == 2) {
        // fused f-partial: f[m, e0+le] += sum_n (acc + b2[n]) * Wo[e0+le, n]
        const float* we = Wo + (size_t)(e0 + le) * 1024;
        float wj[4];
#pragma unroll
        for (int j = 0; j < 4; ++j) wj[j] = we[n0 + wn * 64 + j * 16 + l15];
#pragma unroll
        for (int i = 0; i < 4; ++i) {
            const int mbase = m0 + wm * 64 + i * 16 + q * 4;
#pragma unroll
            for (int r = 0; r < 4; ++r) {
                float sacc = 0.f;
#pragma unroll
                for (int j = 0; j < 4; ++j) sacc += (acc[i][j][r] + bj[j]) * wj[j];
#pragma unroll
                for (int m = 1; m < 16; m <<= 1) sacc += __shfl_xor(sacc, m, 64);
                if (l15 == 0) atomicAdd(&f[(size_t)(mbase + r) * 16 + (e0 + le)], sacc);
            }
        }
    } else {
#pragma unroll
        for (int i = 0; i < 4; ++i) {
            const int mbase = m0 + wm * 64 + i * 16 + q * 4;
#pragma unroll
            for (int r = 0; r < 4; ++r) {
                const size_t rowoff = (size_t)(mbase + r) * 1024;
#pragma unroll
                for (int j = 0; j < 4; ++j) {
                    float v = acc[i][j][r] + bj[j];
                    if (ACT == 0) v = 1.0f / (1.0f + __expf(-v));
                    else          v = fmaxf(v, 0.0f);
                    Ce[rowoff + n0 + wn * 64 + j * 16 + l15] = (_Float16)v;
                }
            }
        }
    }
}

// ---------------------------------------------------- cast x to fp16 --------
__global__ __launch_bounds__(256)
void castx_kernel(const float* __restrict__ x, _Float16* __restrict__ xb)
{
    const size_t i = ((size_t)blockIdx.x * 256 + threadIdx.x) * 8;
    float4 a = *(const float4*)(x + i);
    float4 b = *(const float4*)(x + i + 4);
    half8 h;
    h[0] = (_Float16)a.x; h[1] = (_Float16)a.y; h[2] = (_Float16)a.z; h[3] = (_Float16)a.w;
    h[4] = (_Float16)b.x; h[5] = (_Float16)b.y; h[6] = (_Float16)b.z; h[7] = (_Float16)b.w;
    *(half8*)(xb + i) = h;
}

// ---------------------------------------------------- zero f ----------------
__global__ __launch_bounds__(256)
void zerof_kernel(float* __restrict__ f)
{
    const size_t i = ((size_t)blockIdx.x * 256 + threadIdx.x) * 4;
    float4 z = {0.f, 0.f, 0.f, 0.f};
    *(float4*)(f + i) = z;
}

// --------------------------- transpose+cast W1/W2 -> [E][N][K] fp16 ---------
__global__ __launch_bounds__(256)
void transpose_kernel(const float* __restrict__ W1, const float* __restrict__ W2,
                      _Float16* __restrict__ W1T, _Float16* __restrict__ W2T)
{
    __shared__ _Float16 tile[64][65];
    const int z = blockIdx.z;
    const float* src = (z < 16) ? (W1 + (size_t)z * 1048576ull) : (W2 + (size_t)(z - 16) * 1048576ull);
    _Float16*    dst = (z < 16) ? (W1T + (size_t)z * 1048576ull) : (W2T + (size_t)(z - 16) * 1048576ull);
    const int d0 = blockIdx.y * 64, h0 = blockIdx.x * 64;
    const int tx = threadIdx.x & 63, ty = threadIdx.x >> 6;
#pragma unroll
    for (int r = 0; r < 16; ++r) {
        const int row = r * 4 + ty;
        tile[row][tx] = (_Float16)src[(size_t)(d0 + row) * 1024 + h0 + tx];
    }
    __syncthreads();
#pragma unroll
    for (int r = 0; r < 16; ++r) {
        const int hrow = r * 4 + ty;
        dst[(size_t)(h0 + hrow) * 1024 + d0 + tx] = tile[tx][hrow];
    }
}

// ------------------ gates (fp32, full precision) + softmax + combine --------
__global__ __launch_bounds__(256)
void final_kernel(const float* __restrict__ x,
                  const float* __restrict__ Wg1, const float* __restrict__ bg1,
                  const float* __restrict__ Wg2, const float* __restrict__ bg2,
                  const float* __restrict__ f, const float* __restrict__ bo,
                  float* __restrict__ out)
{
    const int lane = threadIdx.x & 63;
    const int w    = threadIdx.x >> 6;
    const int b    = blockIdx.x * 4 + w;
    const float* xr = x + (size_t)b * 1024;
    float gp1[16], gp2[16];
#pragma unroll
    for (int e = 0; e < 16; ++e) { gp1[e] = 0.f; gp2[e] = 0.f; }
    for (int t = 0; t < 16; ++t) {
        const int d = t * 64 + lane;                 // coalesced x reads
        const float xv = xr[d];
        const float* w1r = Wg1 + (size_t)d * 16;
        const float* w2r = Wg2 + (size_t)d * 16;
#pragma unroll
        for (int e = 0; e < 16; ++e) { gp1[e] += xv * w1r[e]; gp2[e] += xv * w2r[e]; }
    }
#pragma unroll
    for (int e = 0; e < 16; ++e) {
#pragma unroll
        for (int m = 1; m < 64; m <<= 1) {
            gp1[e] += __shfl_xor(gp1[e], m, 64);
            gp2[e] += __shfl_xor(gp2[e], m, 64);
        }
    }
    float a1[16], a2[16], m1 = -1e30f, m2 = -1e30f;
#pragma unroll
    for (int e = 0; e < 16; ++e) {
        a1[e] = gp1[e] + bg1[e]; m1 = fmaxf(m1, a1[e]);
        a2[e] = gp2[e] + bg2[e]; m2 = fmaxf(m2, a2[e]);
    }
    float s1 = 0.f, s2 = 0.f;
#pragma unroll
    for (int e = 0; e < 16; ++e) {
        a1[e] = __expf(a1[e] - m1); s1 += a1[e];
        a2[e] = __expf(a2[e] - m2); s2 += a2[e];
    }
    float o1 = 0.f, o2 = 0.f;
    const float* fb = f + (size_t)b * 16;
#pragma unroll
    for (int e = 0; e < 16; ++e) {
        const float fe = fb[e] + bo[e];
        o1 += a1[e] * fe; o2 += a2[e] * fe;
    }
    if (lane == 0) { out[b] = o1 / s1; out[8192 + b] = o2 / s2; }
}

// ----------------------------------------------------------------------------
extern "C" void kernel_launch(void* const* d_in, const int* in_sizes, int n_in,
                              void* d_out, int out_size, void* d_ws, size_t ws_size,
                              hipStream_t stream)
{
    const float* x   = (const float*)d_in[0];
    const float* W1  = (const float*)d_in[1];
    const float* b1  = (const float*)d_in[2];
    const float* W2  = (const float*)d_in[3];
    const float* b2  = (const float*)d_in[4];
    const float* Wo  = (const float*)d_in[5];
    const float* bo  = (const float*)d_in[6];
    const float* Wg1 = (const float*)d_in[7];
    const float* bg1 = (const float*)d_in[8];
    const float* Wg2 = (const float*)d_in[9];
    const float* bg2 = (const float*)d_in[10];
    float* out = (float*)d_out;

    char* ws = (char*)d_ws;
    _Float16* xb  = (_Float16*)(ws);                         // 16 MB
    _Float16* W1T = (_Float16*)(ws + 16777216ull);           // 32 MB
    _Float16* W2T = (_Float16*)(ws + 50331648ull);           // 32 MB
    float*    f   = (float*)   (ws + 83886080ull);           // 0.5 MB
    char* hbase = ws + 84410368ull;

    // expert-group size: largest that fits ws (deterministic per ws_size)
    int g = 1;
    const int cands[4] = {16, 8, 4, 2};
    for (int ci = 0; ci < 4; ++ci) {
        const size_t need = 84410368ull + 2ull * cands[ci] * 16777216ull;
        if (need <= ws_size) { g = cands[ci]; break; }
    }
    _Float16* h0 = (_Float16*)hbase;
    _Float16* h1 = (_Float16*)(hbase + (size_t)g * 16777216ull);

    castx_kernel<<<4096, 256, 0, stream>>>(x, xb);
    transpose_kernel<<<dim3(16, 16, 32), 256, 0, stream>>>(W1, W2, W1T, W2T);
    zerof_kernel<<<128, 256, 0, stream>>>(f);

    for (int e0 = 0; e0 < 16; e0 += g) {
        gemm_kernel<0><<<dim3(8, 64, g), 256, 0, stream>>>(
            xb, W1T + (size_t)e0 * 1048576ull, b1 + (size_t)e0 * 1024, h0, 0,
            nullptr, nullptr, 0);
        gemm_kernel<1><<<dim3(8, 64, g), 256, 0, stream>>>(
            h0, W2T + (size_t)e0 * 1048576ull, b2 + (size_t)e0 * 1024, h1, 8192ull * 1024ull,
            nullptr, nullptr, 0);
        gemm_kernel<2><<<dim3(8, 64, g), 256, 0, stream>>>(
            h1, W2T + (size_t)e0 * 1048576ull, b2 + (size_t)e0 * 1024, h0, 8192ull * 1024ull,
            Wo, f, e0);
    }
    final_kernel<<<2048, 256, 0, stream>>>(x, Wg1, bg1, Wg2, bg2, f, bo, out);
}

// Round 3
// 1359.644 us; speedup vs baseline: 1.1602x; 1.0165x over previous
//
#include <hip/hip_runtime.h>
#include <hip/hip_bf16.h>
#include <cstdint>
#include <cstddef>

// MultiGateMixExperts: barrier-free fragment-streaming fp16 MFMA GEMMs.
// All GEMM operands live in MFMA-fragment-major layout:
//   frag(tile16 t, kchunk32 c) = 1KB block at ((t*32 + c)*64 + lane)*16B,
//   lane l holds  M[row = t*16 + (l&15)][k = c*32 + (l>>4)*8 + 0..7]  (fp16).
// K-loop: register-double-buffered global_load_dwordx4 + mfma, NO LDS, NO
// __syncthreads -> compiler emits fine-grained vmcnt(N), loads stay in flight.
// h1 = sigmoid(x@W1[e]+b1); h2 = relu(h1@W2[e]+b2);
// f = (h2@W2[e]+b2).Wo[e] fused into stage-3 epilogue (atomicAdd over n-blocks)
// out_i = softmax(x@Wg_i+bg_i) . (f+bo)

using half8   = __attribute__((ext_vector_type(8))) _Float16;
using floatx4 = __attribute__((ext_vector_type(4))) float;

// ---------------------------------------------------------------- GEMM ------
// ACT: 0=sigmoid, 1=relu (writes C in frag layout), 2=f-fused (no C store).
// Block = 4 waves, block tile 128x128, wave tile 64x64 (4x4 of 16x16x32).
// XCD-aware remap: flat%8 = XCD; one expert x contiguous M-stripe per XCD.
template<int ACT>
__global__ __launch_bounds__(256, 2)
void gemm_kernel(const _Float16* __restrict__ A, const _Float16* __restrict__ Bt,
                 const float* __restrict__ bias, _Float16* __restrict__ C,
                 size_t a_estride,
                 const float* __restrict__ Wo, float* __restrict__ f, int e0)
{
    __shared__ _Float16 lt[4][64 * 72];   // per-wave epilogue repack tile

    const int tid  = threadIdx.x;
    const int lane = tid & 63;
    const int w    = tid >> 6;      // wave 0..3
    const int wm   = w & 1;
    const int wn   = w >> 1;

    // --- XCD-aware remap (gridDim = {8, 64, g}) ---
    const int g    = gridDim.z;
    const int flat = blockIdx.x + (blockIdx.y << 3) + (blockIdx.z << 9);
    const int xcd  = flat & 7;
    int s = flat >> 3;
    int le, mb, nb;
    if (g <= 8) {
        const int p = 8 / g;
        le = xcd / p;
        const int stripe = xcd % p;
        nb = s & 7;
        mb = stripe * (64 / p) + (s >> 3);
    } else {
        le = (xcd << 1) | (s >> 9);
        s &= 511;
        nb = s & 7;
        mb = s >> 3;
    }
    const int m0 = mb * 128;
    const int n0 = nb * 128;

    const _Float16* Ae = A   + (size_t)le * a_estride;
    const _Float16* Be = Bt  + (size_t)le * (1024ull * 1024ull);
    const float*    be = bias + (size_t)le * 1024ull;
    _Float16*       Ce = C   + (size_t)le * (8192ull * 1024ull);

    const int mtb = (m0 >> 4) + wm * 4;   // wave's first m-tile
    const int ntb = (n0 >> 4) + wn * 4;   // wave's first n-tile

    // frag pointers (advance by 512 halves per k-chunk)
    const _Float16* pa[4]; const _Float16* pb[4];
#pragma unroll
    for (int i = 0; i < 4; ++i) {
        pa[i] = Ae + ((size_t)(mtb + i) * 32) * 512 + lane * 8;
        pb[i] = Be + ((size_t)(ntb + i) * 32) * 512 + lane * 8;
    }

    floatx4 acc[4][4];
#pragma unroll
    for (int i = 0; i < 4; ++i)
#pragma unroll
        for (int j = 0; j < 4; ++j) { floatx4 z = {0.f, 0.f, 0.f, 0.f}; acc[i][j] = z; }

    half8 a0[4], b0[4], a1[4], b1[4];
#pragma unroll
    for (int i = 0; i < 4; ++i) {                      // preload kc=0
        a0[i] = *(const half8*)pa[i]; pa[i] += 512;
        b0[i] = *(const half8*)pb[i]; pb[i] += 512;
    }

    for (int t = 0; t < 15; ++t) {
#pragma unroll
        for (int i = 0; i < 4; ++i) {                  // load kc=2t+1
            a1[i] = *(const half8*)pa[i]; pa[i] += 512;
            b1[i] = *(const half8*)pb[i]; pb[i] += 512;
        }
#pragma unroll
        for (int i = 0; i < 4; ++i)
#pragma unroll
            for (int j = 0; j < 4; ++j)
                acc[i][j] = __builtin_amdgcn_mfma_f32_16x16x32_f16(a0[i], b0[j], acc[i][j], 0, 0, 0);
#pragma unroll
        for (int i = 0; i < 4; ++i) {                  // load kc=2t+2
            a0[i] = *(const half8*)pa[i]; pa[i] += 512;
            b0[i] = *(const half8*)pb[i]; pb[i] += 512;
        }
#pragma unroll
        for (int i = 0; i < 4; ++i)
#pragma unroll
            for (int j = 0; j < 4; ++j)
                acc[i][j] = __builtin_amdgcn_mfma_f32_16x16x32_f16(a1[i], b1[j], acc[i][j], 0, 0, 0);
    }
#pragma unroll
    for (int i = 0; i < 4; ++i) {                      // load kc=31
        a1[i] = *(const half8*)pa[i];
        b1[i] = *(const half8*)pb[i];
    }
#pragma unroll
    for (int i = 0; i < 4; ++i)
#pragma unroll
        for (int j = 0; j < 4; ++j)
            acc[i][j] = __builtin_amdgcn_mfma_f32_16x16x32_f16(a0[i], b0[j], acc[i][j], 0, 0, 0);
#pragma unroll
    for (int i = 0; i < 4; ++i)
#pragma unroll
        for (int j = 0; j < 4; ++j)
            acc[i][j] = __builtin_amdgcn_mfma_f32_16x16x32_f16(a1[i], b1[j], acc[i][j], 0, 0, 0);

    // ----- epilogue; C/D layout: col=lane&15, row=(lane>>4)*4+r -----
    const int q   = lane >> 4;
    const int l15 = lane & 15;
    float bj[4];
#pragma unroll
    for (int j = 0; j < 4; ++j) bj[j] = be[n0 + wn * 64 + j * 16 + l15];

    if (ACT == 2) {
        // f[m, e0+le] += sum_n (acc + b2[n]) * Wo[e0+le, n]
        const float* we = Wo + (size_t)(e0 + le) * 1024;
        float wj[4];
#pragma unroll
        for (int j = 0; j < 4; ++j) wj[j] = we[n0 + wn * 64 + j * 16 + l15];
#pragma unroll
        for (int i = 0; i < 4; ++i) {
            const int mbase = m0 + wm * 64 + i * 16 + q * 4;
#pragma unroll
            for (int r = 0; r < 4; ++r) {
                float sacc = 0.f;
#pragma unroll
                for (int j = 0; j < 4; ++j) sacc += (acc[i][j][r] + bj[j]) * wj[j];
#pragma unroll
                for (int m = 1; m < 16; m <<= 1) sacc += __shfl_xor(sacc, m, 64);
                if (l15 == 0) atomicAdd(&f[(size_t)(mbase + r) * 16 + (e0 + le)], sacc);
            }
        }
    } else {
        // per-wave LDS repack (no cross-wave access -> no barrier needed)
        _Float16* T = lt[w];
#pragma unroll
        for (int i = 0; i < 4; ++i)
#pragma unroll
            for (int r = 0; r < 4; ++r) {
                const int row = i * 16 + q * 4 + r;
#pragma unroll
                for (int j = 0; j < 4; ++j) {
                    float v = acc[i][j][r] + bj[j];
                    if (ACT == 0) v = 1.0f / (1.0f + __expf(-v));
                    else          v = fmaxf(v, 0.0f);
                    T[row * 72 + j * 16 + l15] = (_Float16)v;
                }
            }
        // read in frag order + vectorized store
        const int kcg0 = ((n0 + wn * 64) >> 5);
#pragma unroll
        for (int i = 0; i < 4; ++i) {
            const int mt = mtb + i;
#pragma unroll
            for (int kci = 0; kci < 2; ++kci) {
                half8 v = *(const half8*)(T + (i * 16 + l15) * 72 + kci * 32 + q * 8);
                *(half8*)(Ce + ((size_t)mt * 32 + kcg0 + kci) * 512 + lane * 8) = v;
            }
        }
    }
}

// --------------------------------------- cast x to fp16 frag layout ---------
// grid (16 k-tiles, 128 m-tiles), 256 threads; 64x64 tile via LDS.
__global__ __launch_bounds__(256)
void castx_kernel(const float* __restrict__ x, _Float16* __restrict__ xb)
{
    __shared__ _Float16 tile[64 * 72];   // [m-local][k-local]
    const int k0 = blockIdx.x * 64;
    const int m0 = blockIdx.y * 64;
    const int tid = threadIdx.x;
    const int col4 = (tid & 15) * 4;
    const int rb   = tid >> 4;           // 0..15
#pragma unroll
    for (int p = 0; p < 4; ++p) {
        const int row = rb + p * 16;
        float4 a = *(const float4*)(x + (size_t)(m0 + row) * 1024 + k0 + col4);
        _Float16* d = tile + row * 72 + col4;
        d[0] = (_Float16)a.x; d[1] = (_Float16)a.y; d[2] = (_Float16)a.z; d[3] = (_Float16)a.w;
    }
    __syncthreads();
    const int lane = tid & 63, w = tid >> 6;
    const int l15 = lane & 15, q = lane >> 4;
#pragma unroll
    for (int ff = 0; ff < 2; ++ff) {
        const int fidx = w * 2 + ff;
        const int mi = fidx >> 1, kci = fidx & 1;
        half8 v = *(const half8*)(tile + (mi * 16 + l15) * 72 + kci * 32 + q * 8);
        const size_t mt = (m0 >> 4) + mi, kc = (k0 >> 5) + kci;
        *(half8*)(xb + (mt * 32 + kc) * 512 + lane * 8) = v;
    }
}

// ------------------- W1/W2 [d][h] fp32 -> frag-major fp16 (n=h, k=d) --------
// grid (16 n-tiles, 16 k-tiles, 32 mats), 256 threads.
__global__ __launch_bounds__(256)
void wtr_kernel(const float* __restrict__ W1, const float* __restrict__ W2,
                _Float16* __restrict__ W1F, _Float16* __restrict__ W2F)
{
    __shared__ _Float16 tile[64 * 73];   // [k-local][n-local], pad 73
    const int z = blockIdx.z;
    const float* src = (z < 16) ? (W1 + (size_t)z * 1048576ull) : (W2 + (size_t)(z - 16) * 1048576ull);
    _Float16*    dst = (z < 16) ? (W1F + (size_t)z * 1048576ull) : (W2F + (size_t)(z - 16) * 1048576ull);
    const int n0 = blockIdx.x * 64;
    const int k0 = blockIdx.y * 64;
    const int tid = threadIdx.x;
    const int col = tid & 63;
    const int rb  = tid >> 6;            // 0..3
#pragma unroll
    for (int p = 0; p < 16; ++p) {
        const int row = rb * 16 + p;
        tile[row * 73 + col] = (_Float16)src[(size_t)(k0 + row) * 1024 + n0 + col];
    }
    __syncthreads();
    const int lane = tid & 63, w = tid >> 6;
    const int l15 = lane & 15, q = lane >> 4;
#pragma unroll
    for (int ff = 0; ff < 2; ++ff) {
        const int fidx = w * 2 + ff;
        const int nti = fidx >> 1, kci = fidx & 1;
        half8 v;
#pragma unroll
        for (int jj = 0; jj < 8; ++jj)
            v[jj] = tile[(kci * 32 + q * 8 + jj) * 73 + nti * 16 + l15];
        const size_t nt = (n0 >> 4) + nti, kc = (k0 >> 5) + kci;
        *(half8*)(dst + (nt * 32 + kc) * 512 + lane * 8) = v;
    }
}

// ---------------------------------------------------- zero f ----------------
__global__ __launch_bounds__(256)
void zerof_kernel(float* __restrict__ f)
{
    const size_t i = ((size_t)blockIdx.x * 256 + threadIdx.x) * 4;
    float4 z = {0.f, 0.f, 0.f, 0.f};
    *(float4*)(f + i) = z;
}

// ------------------ gates (fp32, full precision) + softmax + combine --------
__global__ __launch_bounds__(256)
void final_kernel(const float* __restrict__ x,
                  const float* __restrict__ Wg1, const float* __restrict__ bg1,
                  const float* __restrict__ Wg2, const float* __restrict__ bg2,
                  const float* __restrict__ f, const float* __restrict__ bo,
                  float* __restrict__ out)
{
    const int lane = threadIdx.x & 63;
    const int w    = threadIdx.x >> 6;
    const int b    = blockIdx.x * 4 + w;
    const float* xr = x + (size_t)b * 1024;
    float gp1[16], gp2[16];
#pragma unroll
    for (int e = 0; e < 16; ++e) { gp1[e] = 0.f; gp2[e] = 0.f; }
    for (int t = 0; t < 16; ++t) {
        const int d = t * 64 + lane;
        const float xv = xr[d];
        const float* w1r = Wg1 + (size_t)d * 16;
        const float* w2r = Wg2 + (size_t)d * 16;
#pragma unroll
        for (int e = 0; e < 16; ++e) { gp1[e] += xv * w1r[e]; gp2[e] += xv * w2r[e]; }
    }
#pragma unroll
    for (int e = 0; e < 16; ++e) {
#pragma unroll
        for (int m = 1; m < 64; m <<= 1) {
            gp1[e] += __shfl_xor(gp1[e], m, 64);
            gp2[e] += __shfl_xor(gp2[e], m, 64);
        }
    }
    float a1[16], a2[16], m1 = -1e30f, m2 = -1e30f;
#pragma unroll
    for (int e = 0; e < 16; ++e) {
        a1[e] = gp1[e] + bg1[e]; m1 = fmaxf(m1, a1[e]);
        a2[e] = gp2[e] + bg2[e]; m2 = fmaxf(m2, a2[e]);
    }
    float s1 = 0.f, s2 = 0.f;
#pragma unroll
    for (int e = 0; e < 16; ++e) {
        a1[e] = __expf(a1[e] - m1); s1 += a1[e];
        a2[e] = __expf(a2[e] - m2); s2 += a2[e];
    }
    float o1 = 0.f, o2 = 0.f;
    const float* fb = f + (size_t)b * 16;
#pragma unroll
    for (int e = 0; e < 16; ++e) {
        const float fe = fb[e] + bo[e];
        o1 += a1[e] * fe; o2 += a2[e] * fe;
    }
    if (lane == 0) { out[b] = o1 / s1; out[8192 + b] = o2 / s2; }
}

// ----------------------------------------------------------------------------
extern "C" void kernel_launch(void* const* d_in, const int* in_sizes, int n_in,
                              void* d_out, int out_size, void* d_ws, size_t ws_size,
                              hipStream_t stream)
{
    const float* x   = (const float*)d_in[0];
    const float* W1  = (const float*)d_in[1];
    const float* b1  = (const float*)d_in[2];
    const float* W2  = (const float*)d_in[3];
    const float* b2  = (const float*)d_in[4];
    const float* Wo  = (const float*)d_in[5];
    const float* bo  = (const float*)d_in[6];
    const float* Wg1 = (const float*)d_in[7];
    const float* bg1 = (const float*)d_in[8];
    const float* Wg2 = (const float*)d_in[9];
    const float* bg2 = (const float*)d_in[10];
    float* out = (float*)d_out;

    char* ws = (char*)d_ws;
    _Float16* xb  = (_Float16*)(ws);                         // 16 MB (frag)
    _Float16* W1F = (_Float16*)(ws + 16777216ull);           // 32 MB (frag)
    _Float16* W2F = (_Float16*)(ws + 50331648ull);           // 32 MB (frag)
    float*    f   = (float*)   (ws + 83886080ull);           // 0.5 MB
    char* hbase = ws + 84410368ull;

    int g = 1;
    const int cands[4] = {16, 8, 4, 2};
    for (int ci = 0; ci < 4; ++ci) {
        const size_t need = 84410368ull + 2ull * cands[ci] * 16777216ull;
        if (need <= ws_size) { g = cands[ci]; break; }
    }
    _Float16* h0 = (_Float16*)hbase;
    _Float16* h1 = (_Float16*)(hbase + (size_t)g * 16777216ull);

    castx_kernel<<<dim3(16, 128), 256, 0, stream>>>(x, xb);
    wtr_kernel<<<dim3(16, 16, 32), 256, 0, stream>>>(W1, W2, W1F, W2F);
    zerof_kernel<<<128, 256, 0, stream>>>(f);

    for (int e0 = 0; e0 < 16; e0 += g) {
        gemm_kernel<0><<<dim3(8, 64, g), 256, 0, stream>>>(
            xb, W1F + (size_t)e0 * 1048576ull, b1 + (size_t)e0 * 1024, h0, 0,
            nullptr, nullptr, 0);
        gemm_kernel<1><<<dim3(8, 64, g), 256, 0, stream>>>(
            h0, W2F + (size_t)e0 * 1048576ull, b2 + (size_t)e0 * 1024, h1, 8192ull * 1024ull,
            nullptr, nullptr, 0);
        gemm_kernel<2><<<dim3(8, 64, g), 256, 0, stream>>>(
            h1, W2F + (size_t)e0 * 1048576ull, b2 + (size_t)e0 * 1024, h0, 8192ull * 1024ull,
            Wo, f, e0);
    }
    final_kernel<<<2048, 256, 0, stream>>>(x, Wg1, bg1, Wg2, bg2, f, bo, out);
}